// Round 3
// baseline (778.026 us; speedup 1.0000x reference)
//
#include <hip/hip_runtime.h>
#include <hip/hip_bf16.h>

// Problem constants (reference: N, E, K, F_IN, H = 50000, 640000, 3, 128, 128)
#define NN 50000
#define NE 640000

typedef unsigned short ushort_t;
typedef unsigned int uint_t;
typedef __attribute__((ext_vector_type(8))) short bf16x8;   // 8 bf16 = 4 VGPRs
typedef __attribute__((ext_vector_type(4))) float f32x4;

__device__ __forceinline__ float b2f(ushort_t u) {
    union { uint_t u; float f; } v; v.u = ((uint_t)u) << 16; return v.f;
}
__device__ __forceinline__ ushort_t f2b(float f) {
    union { float f; uint_t u; } v; v.f = f;
    uint_t u = v.u;
    uint_t r = u + 0x7fffu + ((u >> 16) & 1u);   // round-nearest-even
    return (ushort_t)(r >> 16);
}
__device__ __forceinline__ float sigf(float x) { return 1.0f / (1.0f + expf(-x)); }
// mode-aware scalar param load: mf=1 -> f32 array, mf=0 -> bf16 array
__device__ __forceinline__ float ldm(const void* p, int i, int mf) {
    return mf ? ((const float*)p)[i] : b2f(((const ushort_t*)p)[i]);
}

// ---- workspace layout (bytes), total < 38.94 MB (was 51.7 MB — ws_size hedge) ----
// hb  : NN*128 bf16 @ 0            (12,800,000)
// g   : NN*128 f32  @ 12,800,000   (25,600,000)
// dg  : NN f32      @ 38,400,000   (200,000)
// cnt : NN i32      @ 38,600,000   (200,000)
// WT  : 4*16384 bf16@ 38,800,000   (131,072)  Wi^T, Wc^T, Wo^T, gcn_w^T  ([f][k])
// coef: 641 f32     @ 38,931,072   (2,564)
// mode: 1 i32       @ 38,933,648
#define OFF_HB   0
#define OFF_G    12800000
#define OFF_DG   38400000
#define OFF_CNT  38600000
#define OFF_WT   38800000
#define OFF_COEF 38931072
#define OFF_MODE 38933648
#define WS_REQ   38933656

// ---------------------------------------------------------------------------
// dtype detector: interpret first 4096 u16 of x as bf16. If x is really f32,
// the mantissa-low halves are uniform random -> ~25% have exponent >= 0xC0
// (|v| >= 2^65). Real bf16 N(0,1) data: exponent <= ~0x82, zero hits.
// ---------------------------------------------------------------------------
__global__ void detect_k(const ushort_t* __restrict__ x, int* __restrict__ mode) {
    int t = threadIdx.x;
    int bad = 0;
    for (int i = t; i < 4096; i += 256) {
        int e = (x[i] >> 7) & 0xFF;
        if (e >= 0xC0) bad++;
    }
    __shared__ int s[256];
    s[t] = bad; __syncthreads();
    for (int o = 128; o >= 1; o >>= 1) { if (t < o) s[t] += s[t + o]; __syncthreads(); }
    if (t == 0) mode[0] = (s[0] > 8) ? 1 : 0;   // 1 = f32 inputs, 0 = bf16 inputs
}

__global__ void zero_k(int* __restrict__ cnt) {
    int n = blockIdx.x * blockDim.x + threadIdx.x;
    if (n < NN) cnt[n] = 0;
}

__global__ void fb_k(ushort_t* __restrict__ out, int n) {   // ws too small: diagnostic zeros
    int i = blockIdx.x * blockDim.x + threadIdx.x;
    if (i < n) out[i] = 0;
}

// ---------------------------------------------------------------------------
// prep: transpose W_x[0],W_x[2],W_x[3],gcn_w into bf16 [f][k]; fold biases
// (cheb(0)=theta_b), peephole w_c[2], and relu->BN->linear tail into s[f], C.
// All param reads go through ldm() with the detected dtype.
// ---------------------------------------------------------------------------
__global__ void prep_k(const void* __restrict__ Wx, const void* __restrict__ gcnw,
                       const void* __restrict__ wc, const void* __restrict__ bb,
                       const void* __restrict__ thb,
                       const void* __restrict__ gam, const void* __restrict__ bet,
                       const void* __restrict__ mea, const void* __restrict__ var,
                       const void* __restrict__ linw, const void* __restrict__ linb,
                       const int* __restrict__ mode,
                       ushort_t* __restrict__ WT, float* __restrict__ coef) {
    int t = threadIdx.x;  // 256 threads
    int mf = mode[0];
    const int srcoff[4] = { 0, 2 * 16384, 3 * 16384, 0 };
    for (int m = 0; m < 4; m++) {
        const void* S = (m == 3) ? gcnw : Wx;
        int so = srcoff[m];
        ushort_t* D = WT + m * 16384;
        for (int idx = t; idx < 16384; idx += 256) {
            int f = idx >> 7, k = idx & 127;
            float v = ldm(S, so + k * 128 + f, mf);
            D[idx] = f2b(v);                       // exact pass-through when bf16
        }
    }
    __shared__ float red[128];
    if (t < 128) {
        float bi = ldm(thb, t, mf)           + ldm(bb, t, mf);
        float bc = ldm(thb, 2 * 128 + t, mf) + ldm(bb, 2 * 128 + t, mf);
        float bo = ldm(thb, 3 * 128 + t, mf) + ldm(bb, 3 * 128 + t, mf);
        float w2 = ldm(wc, 2 * 128 + t, mf);
        float rs = rsqrtf(ldm(var, t, mf) + 1e-5f);
        float ga = ldm(gam, t, mf);
        float lw = ldm(linw, t, mf);
        coef[t]         = bi;
        coef[128 + t]   = bc;
        coef[256 + t]   = bo;
        coef[384 + t]   = w2;
        coef[512 + t]   = ga * rs * lw;                              // s[f]
        red[t] = (ldm(bet, t, mf) - ldm(mea, t, mf) * ga * rs) * lw; // constant term
    }
    __syncthreads();
    for (int off = 64; off >= 1; off >>= 1) {
        if (t < off) red[t] += red[t + off];
        __syncthreads();
    }
    if (t == 0) coef[640] = red[0] + ldm(linb, 0, mf);               // C
}

// GCN degree: deg_g[i] = 1 + (# edges with dst == i)
__global__ void degree_k(const int* __restrict__ ei, int* __restrict__ cnt) {
    int e = blockIdx.x * blockDim.x + threadIdx.x;
    if (e < NE) atomicAdd(&cnt[ei[NE + e]], 1);
}

__global__ void dg_k(const int* __restrict__ cnt, float* __restrict__ dg) {
    int n = blockIdx.x * blockDim.x + threadIdx.x;
    if (n < NN) {
        int c = cnt[n];
        if (c < 0) c = 0;
        dg[n] = rsqrtf(1.0f + (float)c);
    }
}

// ---------------------------------------------------------------------------
// Fused gates + gcn GEMM. One block = 4 waves = 64 nodes; wave w owns rows
// [16w,16w+16) of the LDS tile in both stages (no cross-wave hazard).
// MFMA f32_16x16x32_bf16 layouts (HW-verified):
//   A: a[j] = A[m=lane&15][k=(lane>>4)*8+j]
//   B: b[j] = B[k=(lane>>4)*8+j][n=lane&15]   (WT [f][k] -> contiguous 16B)
//   D: reg r -> row (lane>>4)*4+r, col lane&15
// ---------------------------------------------------------------------------
__launch_bounds__(256)
__global__ void gates_k(const void* __restrict__ x, const ushort_t* __restrict__ WT,
                        const float* __restrict__ coef, const float* __restrict__ dg,
                        const void* __restrict__ gcnb, const int* __restrict__ mode,
                        ushort_t* __restrict__ hb, float* __restrict__ g) {
    __shared__ ushort_t tile[64 * 136];   // +8 pad: row stride 272B
    int t = threadIdx.x;
    int base = blockIdx.x * 64;
    int mf = mode[0];

    // stage x tile: 64 rows x 128 cols, 8 elems/thread/iter, dtype-aware
    for (int i = 0; i < 4; i++) {
        int idx = (i * 256 + t) * 8;
        int row = idx >> 7, col = idx & 127;
        int n = base + row;
        bf16x8 v;
        if (n >= NN) {
            v = (bf16x8)0;
        } else if (mf == 0) {
            v = *(const bf16x8*)((const ushort_t*)x + n * 128 + col);
        } else {
            const float* xf = (const float*)x + n * 128 + col;
            float4 lo = *(const float4*)xf;
            float4 hi = *(const float4*)(xf + 4);
            v[0] = (short)f2b(lo.x); v[1] = (short)f2b(lo.y);
            v[2] = (short)f2b(lo.z); v[3] = (short)f2b(lo.w);
            v[4] = (short)f2b(hi.x); v[5] = (short)f2b(hi.y);
            v[6] = (short)f2b(hi.z); v[7] = (short)f2b(hi.w);
        }
        *(bf16x8*)&tile[row * 136 + col] = v;
    }
    __syncthreads();

    int lane = t & 63, wave = t >> 6;
    int m = lane & 15, quad = lane >> 4;
    int rowA = wave * 16 + m;

    bf16x8 a[4];
    #pragma unroll
    for (int kt = 0; kt < 4; kt++)
        a[kt] = *(const bf16x8*)&tile[rowA * 136 + kt * 32 + quad * 8];
    __syncthreads();   // all x reads done before Hs overwrites tile

    const ushort_t* WTi = WT;
    const ushort_t* WTc = WT + 16384;
    const ushort_t* WTo = WT + 2 * 16384;

    #pragma unroll
    for (int ft = 0; ft < 8; ft++) {
        int f = ft * 16 + m;
        f32x4 ai = {0,0,0,0}, ac = {0,0,0,0}, ao = {0,0,0,0};
        #pragma unroll
        for (int kt = 0; kt < 4; kt++) {
            int off = f * 128 + kt * 32 + quad * 8;
            bf16x8 bi = *(const bf16x8*)(WTi + off);
            bf16x8 bc = *(const bf16x8*)(WTc + off);
            bf16x8 bo = *(const bf16x8*)(WTo + off);
            ai = __builtin_amdgcn_mfma_f32_16x16x32_bf16(a[kt], bi, ai, 0, 0, 0);
            ac = __builtin_amdgcn_mfma_f32_16x16x32_bf16(a[kt], bc, ac, 0, 0, 0);
            ao = __builtin_amdgcn_mfma_f32_16x16x32_bf16(a[kt], bo, ao, 0, 0, 0);
        }
        float bi_f = coef[f], bc_f = coef[128 + f], bo_f = coef[256 + f], w2 = coef[384 + f];
        #pragma unroll
        for (int r = 0; r < 4; r++) {
            float I  = sigf(ai[r] + bi_f);
            float T  = tanhf(ac[r] + bc_f);
            float Cs = I * T;                       // F*C_prev = 0
            float O  = sigf(ao[r] + w2 * Cs + bo_f);
            float Hs = O * tanhf(Cs);
            tile[(wave * 16 + quad * 4 + r) * 136 + f] = f2b(Hs);
        }
    }
    __syncthreads();   // Hs tile complete before stage-2 reads

    const ushort_t* WTg = WT + 3 * 16384;
    bf16x8 ah[4];
    #pragma unroll
    for (int kt = 0; kt < 4; kt++)
        ah[kt] = *(const bf16x8*)&tile[rowA * 136 + kt * 32 + quad * 8];

    #pragma unroll
    for (int ft = 0; ft < 8; ft++) {
        int f = ft * 16 + m;
        f32x4 acc = {0,0,0,0};
        #pragma unroll
        for (int kt = 0; kt < 4; kt++) {
            bf16x8 bg = *(const bf16x8*)(WTg + f * 128 + kt * 32 + quad * 8);
            acc = __builtin_amdgcn_mfma_f32_16x16x32_bf16(ah[kt], bg, acc, 0, 0, 0);
        }
        float gb = ldm(gcnb, f, mf);
        #pragma unroll
        for (int r = 0; r < 4; r++) {
            int n = base + wave * 16 + quad * 4 + r;
            if (n < NN) {
                float hv = acc[r];
                float d = dg[n];
                hb[n * 128 + f] = f2b(hv);          // h stored bf16 (halves scatter reads)
                g[n * 128 + f]  = d * d * hv + gb;  // self-loop + bias
            }
        }
    }
}

// scatter: one wave per edge; lane covers 2 feats (one dword load, 2 atomics)
__global__ void scatter_k(const int* __restrict__ ei, const float* __restrict__ dg,
                          const ushort_t* __restrict__ hb, float* __restrict__ g) {
    int wid  = (blockIdx.x * blockDim.x + threadIdx.x) >> 6;
    int lane = threadIdx.x & 63;
    int nw   = (gridDim.x * blockDim.x) >> 6;
    for (int e = wid; e < NE; e += nw) {
        int s = ei[e], d = ei[NE + e];
        float c = dg[s] * dg[d];
        uint_t pr = *(const uint_t*)(hb + s * 128 + lane * 2);
        float v0 = b2f((ushort_t)(pr & 0xffffu));
        float v1 = b2f((ushort_t)(pr >> 16));
        float* gd = g + d * 128 + lane * 2;
        __hip_atomic_fetch_add(gd,     c * v0, __ATOMIC_RELAXED, __HIP_MEMORY_SCOPE_AGENT);
        __hip_atomic_fetch_add(gd + 1, c * v1, __ATOMIC_RELAXED, __HIP_MEMORY_SCOPE_AGENT);
    }
}

// out[n] = sum_f relu(g[n,f]) * s[f] + C, one wave/node; store width per mode
__global__ void out_k(const float* __restrict__ g, const float* __restrict__ coef,
                      const int* __restrict__ mode, void* __restrict__ out) {
    int wid  = (blockIdx.x * blockDim.x + threadIdx.x) >> 6;
    int lane = threadIdx.x & 63;
    if (wid >= NN) return;
    const float* gr = g + wid * 128;
    float v = fmaxf(gr[lane], 0.0f)      * coef[512 + lane]
            + fmaxf(gr[lane + 64], 0.0f) * coef[512 + 64 + lane];
    #pragma unroll
    for (int o = 32; o >= 1; o >>= 1) v += __shfl_down(v, o);
    if (lane == 0) {
        float r = v + coef[640];
        if (mode[0]) ((float*)out)[wid] = r;
        else         ((ushort_t*)out)[wid] = f2b(r);
    }
}

extern "C" void kernel_launch(void* const* d_in, const int* in_sizes, int n_in,
                              void* d_out, int out_size, void* d_ws, size_t ws_size,
                              hipStream_t stream) {
    if (ws_size < (size_t)WS_REQ) {   // diagnostic: finite 0.088 failure, not NaN
        fb_k<<<(out_size + 255) / 256, 256, 0, stream>>>((ushort_t*)d_out, out_size);
        return;
    }
    const void* x    = d_in[0];
    const int*  ei   = (const int*)d_in[1];
    // d_in[2] edge_weight: unused (ChebConv of zero state collapses to bias)
    const void* Wx   = d_in[3];
    const void* wc   = d_in[4];
    const void* bb   = d_in[5];
    // d_in[6] theta: unused
    const void* thb  = d_in[7];
    const void* gcnw = d_in[8];
    const void* gcnb = d_in[9];
    const void* gam  = d_in[10];
    const void* bet  = d_in[11];
    const void* mea  = d_in[12];
    const void* var  = d_in[13];
    const void* linw = d_in[14];
    const void* linb = d_in[15];

    char* ws = (char*)d_ws;
    ushort_t* hb   = (ushort_t*)(ws + OFF_HB);
    float*    g    = (float*)   (ws + OFF_G);
    float*    dg   = (float*)   (ws + OFF_DG);
    int*      cnt  = (int*)     (ws + OFF_CNT);
    ushort_t* WT   = (ushort_t*)(ws + OFF_WT);
    float*    coef = (float*)   (ws + OFF_COEF);
    int*      mode = (int*)     (ws + OFF_MODE);

    detect_k<<<1, 256, 0, stream>>>((const ushort_t*)x, mode);
    zero_k<<<(NN + 255) / 256, 256, 0, stream>>>(cnt);
    prep_k<<<1, 256, 0, stream>>>(Wx, gcnw, wc, bb, thb, gam, bet, mea, var, linw, linb, mode, WT, coef);
    degree_k<<<(NE + 255) / 256, 256, 0, stream>>>(ei, cnt);
    dg_k<<<(NN + 255) / 256, 256, 0, stream>>>(cnt, dg);
    gates_k<<<(NN + 63) / 64, 256, 0, stream>>>(x, WT, coef, dg, gcnb, mode, hb, g);
    scatter_k<<<1280, 256, 0, stream>>>(ei, dg, hb, g);
    out_k<<<(NN * 64 + 255) / 256, 256, 0, stream>>>(g, coef, mode, d_out);
}

// Round 4
// 431.974 us; speedup vs baseline: 1.8011x; 1.8011x over previous
//
#include <hip/hip_runtime.h>
#include <hip/hip_bf16.h>

// Problem constants (reference: N, E, K, F_IN, H = 50000, 640000, 3, 128, 128)
#define NN 50000
#define NE 640000

typedef unsigned short ushort_t;
typedef unsigned int uint_t;
typedef __attribute__((ext_vector_type(8))) short bf16x8;   // 8 bf16 = 4 VGPRs
typedef __attribute__((ext_vector_type(4))) float f32x4;

__device__ __forceinline__ float b2f(ushort_t u) {
    union { uint_t u; float f; } v; v.u = ((uint_t)u) << 16; return v.f;
}
__device__ __forceinline__ ushort_t f2b(float f) {
    union { float f; uint_t u; } v; v.f = f;
    uint_t u = v.u;
    uint_t r = u + 0x7fffu + ((u >> 16) & 1u);   // round-nearest-even
    return (ushort_t)(r >> 16);
}
__device__ __forceinline__ float sigf(float x) { return 1.0f / (1.0f + expf(-x)); }
// mode-aware scalar param load: mf=1 -> f32 array, mf=0 -> bf16 array
__device__ __forceinline__ float ldm(const void* p, int i, int mf) {
    return mf ? ((const float*)p)[i] : b2f(((const ushort_t*)p)[i]);
}

// ---- workspace layout (bytes), total 31.65 MB (known-good: 38.93 MB passed R3) ----
// h    : NN*128 f32 @ 0            (25,600,000)   post-gcn_w features, fp32
// dg   : NN f32     @ 25,600,000   (200,000)
// cnt  : NN i32     @ 25,800,000   (200,000)
// offs : NN i32     @ 26,000,000   (200,000)      CSR row start
// cur  : NN i32     @ 26,200,000   (200,000)      fill cursor; post-fill = row end
// bsrc : NE i32     @ 26,400,000   (2,560,000)    bucketed source node
// bc   : NE f32     @ 28,960,000   (2,560,000)    bucketed dg[s]*dg[d]
// WT   : 4*16384 b16@ 31,520,000   (131,072)      Wi^T, Wc^T, Wo^T, gcn_w^T ([f][k])
// coef : 641 f32    @ 31,651,072   (2,564)
// mode : 1 i32      @ 31,653,640
#define OFF_H    0
#define OFF_DG   25600000
#define OFF_CNT  25800000
#define OFF_OFFS 26000000
#define OFF_CUR  26200000
#define OFF_BSRC 26400000
#define OFF_BC   28960000
#define OFF_WT   31520000
#define OFF_COEF 31651072
#define OFF_MODE 31653640
#define WS_REQ   31653648

// dtype detector: f32-as-bf16 halves show huge exponents (~25% >= 0xC0);
// real bf16 N(0,1) never does.
__global__ void detect_k(const ushort_t* __restrict__ x, int* __restrict__ mode) {
    int t = threadIdx.x;
    int bad = 0;
    for (int i = t; i < 4096; i += 256) {
        int e = (x[i] >> 7) & 0xFF;
        if (e >= 0xC0) bad++;
    }
    __shared__ int s[256];
    s[t] = bad; __syncthreads();
    for (int o = 128; o >= 1; o >>= 1) { if (t < o) s[t] += s[t + o]; __syncthreads(); }
    if (t == 0) mode[0] = (s[0] > 8) ? 1 : 0;   // 1 = f32 inputs, 0 = bf16 inputs
}

__global__ void zero_k(int* __restrict__ cnt) {
    int n = blockIdx.x * blockDim.x + threadIdx.x;
    if (n < NN) cnt[n] = 0;
}

__global__ void fb_k(ushort_t* __restrict__ out, int n) {   // ws too small: diagnostic zeros
    int i = blockIdx.x * blockDim.x + threadIdx.x;
    if (i < n) out[i] = 0;
}

// transpose W_x[0],W_x[2],W_x[3],gcn_w -> bf16 [f][k]; 64 blocks (R3's 1-block was serial)
__global__ void prep_w_k(const void* __restrict__ Wx, const void* __restrict__ gcnw,
                         const int* __restrict__ mode, ushort_t* __restrict__ WT) {
    int gid = blockIdx.x * blockDim.x + threadIdx.x;   // 16384 threads, 1 elem/matrix
    if (gid >= 16384) return;
    int mf = mode[0];
    int f = gid >> 7, k = gid & 127;
    const int srcoff[4] = { 0, 2 * 16384, 3 * 16384, 0 };
    #pragma unroll
    for (int m = 0; m < 4; m++) {
        const void* S = (m == 3) ? gcnw : Wx;
        WT[m * 16384 + gid] = f2b(ldm(S, srcoff[m] + k * 128 + f, mf));
    }
}

// fold gate biases (cheb(0)=theta_b), peephole w_c[2], relu->BN->linear tail
__global__ void prep_c_k(const void* __restrict__ wc, const void* __restrict__ bb,
                         const void* __restrict__ thb,
                         const void* __restrict__ gam, const void* __restrict__ bet,
                         const void* __restrict__ mea, const void* __restrict__ var,
                         const void* __restrict__ linw, const void* __restrict__ linb,
                         const int* __restrict__ mode, float* __restrict__ coef) {
    int t = threadIdx.x;  // 256
    int mf = mode[0];
    __shared__ float red[128];
    if (t < 128) {
        float rs = rsqrtf(ldm(var, t, mf) + 1e-5f);
        float ga = ldm(gam, t, mf);
        float lw = ldm(linw, t, mf);
        coef[t]         = ldm(thb, t, mf)           + ldm(bb, t, mf);            // bias_i
        coef[128 + t]   = ldm(thb, 2 * 128 + t, mf) + ldm(bb, 2 * 128 + t, mf);  // bias_c
        coef[256 + t]   = ldm(thb, 3 * 128 + t, mf) + ldm(bb, 3 * 128 + t, mf);  // bias_o
        coef[384 + t]   = ldm(wc, 2 * 128 + t, mf);                              // w_c[2]
        coef[512 + t]   = ga * rs * lw;                                          // s[f]
        red[t] = (ldm(bet, t, mf) - ldm(mea, t, mf) * ga * rs) * lw;
    }
    __syncthreads();
    for (int off = 64; off >= 1; off >>= 1) {
        if (t < off) red[t] += red[t + off];
        __syncthreads();
    }
    if (t == 0) coef[640] = red[0] + ldm(linb, 0, mf);                           // C
}

__global__ void degree_k(const int* __restrict__ ei, int* __restrict__ cnt) {
    int e = blockIdx.x * blockDim.x + threadIdx.x;
    if (e < NE) atomicAdd(&cnt[ei[NE + e]], 1);
}

// single-block scan: offs/cur = exclusive prefix of cnt; dg = rsqrt(1+deg)
#define SCAN_T 1024
__global__ void scan_k(const int* __restrict__ cnt, int* __restrict__ offs,
                       int* __restrict__ cur, float* __restrict__ dg) {
    __shared__ int sp[SCAN_T];
    int t = threadIdx.x;
    const int chunk = (NN + SCAN_T - 1) / SCAN_T;   // 49
    int b = t * chunk, e = b + chunk; if (e > NN) e = NN; if (b > NN) b = NN;
    int sum = 0;
    for (int i = b; i < e; i++) sum += cnt[i];
    sp[t] = sum; __syncthreads();
    for (int o = 1; o < SCAN_T; o <<= 1) {
        int v = (t >= o) ? sp[t - o] : 0;
        __syncthreads();
        sp[t] += v;
        __syncthreads();
    }
    int run = (t == 0) ? 0 : sp[t - 1];
    for (int i = b; i < e; i++) {
        offs[i] = run;
        cur[i]  = run;
        int c = cnt[i]; if (c < 0) c = 0;
        dg[i] = rsqrtf(1.0f + (float)c);
        run += cnt[i];
    }
}

// bucket edges by destination; precompute per-edge coefficient
__global__ void fill_k(const int* __restrict__ ei, const float* __restrict__ dg,
                       int* __restrict__ cur, int* __restrict__ bsrc, float* __restrict__ bc) {
    int e = blockIdx.x * blockDim.x + threadIdx.x;
    if (e < NE) {
        int s = ei[e], d = ei[NE + e];
        int pos = atomicAdd(&cur[d], 1);
        bsrc[pos] = s;
        bc[pos]   = dg[s] * dg[d];
    }
}

// ---------------------------------------------------------------------------
// Fused gates + gcn GEMM -> h (f32). One block = 4 waves = 64 nodes; wave w
// owns LDS rows [16w,16w+16) in both stages. MFMA f32_16x16x32_bf16 layouts:
//   A: a[j]=A[m=lane&15][k=(lane>>4)*8+j];  B: b[j]=B[k=(lane>>4)*8+j][n=lane&15]
//   D: reg r -> row (lane>>4)*4+r, col lane&15
// ---------------------------------------------------------------------------
__launch_bounds__(256)
__global__ void gates_k(const void* __restrict__ x, const ushort_t* __restrict__ WT,
                        const float* __restrict__ coef, const int* __restrict__ mode,
                        float* __restrict__ h) {
    __shared__ ushort_t tile[64 * 136];   // +8 pad: row stride 272B
    int t = threadIdx.x;
    int base = blockIdx.x * 64;
    int mf = mode[0];

    for (int i = 0; i < 4; i++) {
        int idx = (i * 256 + t) * 8;
        int row = idx >> 7, col = idx & 127;
        int n = base + row;
        bf16x8 v;
        if (n >= NN) {
            v = (bf16x8)0;
        } else if (mf == 0) {
            v = *(const bf16x8*)((const ushort_t*)x + n * 128 + col);
        } else {
            const float* xf = (const float*)x + n * 128 + col;
            float4 lo = *(const float4*)xf;
            float4 hi = *(const float4*)(xf + 4);
            v[0] = (short)f2b(lo.x); v[1] = (short)f2b(lo.y);
            v[2] = (short)f2b(lo.z); v[3] = (short)f2b(lo.w);
            v[4] = (short)f2b(hi.x); v[5] = (short)f2b(hi.y);
            v[6] = (short)f2b(hi.z); v[7] = (short)f2b(hi.w);
        }
        *(bf16x8*)&tile[row * 136 + col] = v;
    }
    __syncthreads();

    int lane = t & 63, wave = t >> 6;
    int m = lane & 15, quad = lane >> 4;
    int rowA = wave * 16 + m;

    bf16x8 a[4];
    #pragma unroll
    for (int kt = 0; kt < 4; kt++)
        a[kt] = *(const bf16x8*)&tile[rowA * 136 + kt * 32 + quad * 8];
    __syncthreads();   // all x reads done before Hs overwrites tile

    const ushort_t* WTi = WT;
    const ushort_t* WTc = WT + 16384;
    const ushort_t* WTo = WT + 2 * 16384;

    #pragma unroll
    for (int ft = 0; ft < 8; ft++) {
        int f = ft * 16 + m;
        f32x4 ai = {0,0,0,0}, ac = {0,0,0,0}, ao = {0,0,0,0};
        #pragma unroll
        for (int kt = 0; kt < 4; kt++) {
            int off = f * 128 + kt * 32 + quad * 8;
            bf16x8 bi = *(const bf16x8*)(WTi + off);
            bf16x8 bc8 = *(const bf16x8*)(WTc + off);
            bf16x8 bo = *(const bf16x8*)(WTo + off);
            ai = __builtin_amdgcn_mfma_f32_16x16x32_bf16(a[kt], bi,  ai, 0, 0, 0);
            ac = __builtin_amdgcn_mfma_f32_16x16x32_bf16(a[kt], bc8, ac, 0, 0, 0);
            ao = __builtin_amdgcn_mfma_f32_16x16x32_bf16(a[kt], bo,  ao, 0, 0, 0);
        }
        float bi_f = coef[f], bc_f = coef[128 + f], bo_f = coef[256 + f], w2 = coef[384 + f];
        #pragma unroll
        for (int r = 0; r < 4; r++) {
            float I  = sigf(ai[r] + bi_f);
            float T  = tanhf(ac[r] + bc_f);
            float Cs = I * T;                       // F*C_prev = 0
            float O  = sigf(ao[r] + w2 * Cs + bo_f);
            float Hs = O * tanhf(Cs);
            tile[(wave * 16 + quad * 4 + r) * 136 + f] = f2b(Hs);
        }
    }
    __syncthreads();   // Hs tile complete before stage-2 reads

    const ushort_t* WTg = WT + 3 * 16384;
    bf16x8 ah[4];
    #pragma unroll
    for (int kt = 0; kt < 4; kt++)
        ah[kt] = *(const bf16x8*)&tile[rowA * 136 + kt * 32 + quad * 8];

    #pragma unroll
    for (int ft = 0; ft < 8; ft++) {
        int f = ft * 16 + m;
        f32x4 acc = {0,0,0,0};
        #pragma unroll
        for (int kt = 0; kt < 4; kt++) {
            bf16x8 bg = *(const bf16x8*)(WTg + f * 128 + kt * 32 + quad * 8);
            acc = __builtin_amdgcn_mfma_f32_16x16x32_bf16(ah[kt], bg, acc, 0, 0, 0);
        }
        #pragma unroll
        for (int r = 0; r < 4; r++) {
            int n = base + wave * 16 + quad * 4 + r;
            if (n < NN) h[n * 128 + f] = acc[r];
        }
    }
}

// ---------------------------------------------------------------------------
// Fused gather + self-loop + relu->BN->linear. One wave per destination node,
// 2 feats/lane, fp32 accumulation in registers — zero atomics.
// ---------------------------------------------------------------------------
__launch_bounds__(256)
__global__ void gat_out_k(const float* __restrict__ h, const int* __restrict__ offs,
                          const int* __restrict__ cur, const int* __restrict__ bsrc,
                          const float* __restrict__ bc, const float* __restrict__ dg,
                          const void* __restrict__ gcnb, const float* __restrict__ coef,
                          const int* __restrict__ mode, void* __restrict__ out) {
    int wid  = (blockIdx.x * blockDim.x + threadIdx.x) >> 6;
    int lane = threadIdx.x & 63;
    if (wid >= NN) return;
    int beg = offs[wid], end = cur[wid];   // cur post-fill == row end
    float a0 = 0.0f, a1 = 0.0f;
    int j = beg;
    for (; j + 1 < end; j += 2) {          // 2-way unroll: overlap the row loads
        int s0 = bsrc[j], s1 = bsrc[j + 1];
        float c0 = bc[j], c1 = bc[j + 1];
        float2 v0 = *(const float2*)(h + s0 * 128 + lane * 2);
        float2 v1 = *(const float2*)(h + s1 * 128 + lane * 2);
        a0 += c0 * v0.x + c1 * v1.x;
        a1 += c0 * v0.y + c1 * v1.y;
    }
    if (j < end) {
        int s = bsrc[j]; float c = bc[j];
        float2 v = *(const float2*)(h + s * 128 + lane * 2);
        a0 += c * v.x; a1 += c * v.y;
    }
    int mf = mode[0];
    float2 hv = *(const float2*)(h + wid * 128 + lane * 2);
    float d2 = dg[wid] * dg[wid];
    float g0 = a0 + d2 * hv.x + ldm(gcnb, lane * 2,     mf);
    float g1 = a1 + d2 * hv.y + ldm(gcnb, lane * 2 + 1, mf);
    float v = fmaxf(g0, 0.0f) * coef[512 + lane * 2]
            + fmaxf(g1, 0.0f) * coef[512 + lane * 2 + 1];
    #pragma unroll
    for (int o = 32; o >= 1; o >>= 1) v += __shfl_down(v, o);
    if (lane == 0) {
        float r = v + coef[640];
        if (mf) ((float*)out)[wid] = r;
        else    ((ushort_t*)out)[wid] = f2b(r);
    }
}

extern "C" void kernel_launch(void* const* d_in, const int* in_sizes, int n_in,
                              void* d_out, int out_size, void* d_ws, size_t ws_size,
                              hipStream_t stream) {
    if (ws_size < (size_t)WS_REQ) {   // diagnostic: finite 0.088 failure, not NaN
        fb_k<<<(out_size + 255) / 256, 256, 0, stream>>>((ushort_t*)d_out, out_size);
        return;
    }
    const void* x    = d_in[0];
    const int*  ei   = (const int*)d_in[1];
    // d_in[2] edge_weight: unused (ChebConv of zero state collapses to bias)
    const void* Wx   = d_in[3];
    const void* wc   = d_in[4];
    const void* bb   = d_in[5];
    // d_in[6] theta: unused
    const void* thb  = d_in[7];
    const void* gcnw = d_in[8];
    const void* gcnb = d_in[9];
    const void* gam  = d_in[10];
    const void* bet  = d_in[11];
    const void* mea  = d_in[12];
    const void* var  = d_in[13];
    const void* linw = d_in[14];
    const void* linb = d_in[15];

    char* ws = (char*)d_ws;
    float*    h    = (float*)   (ws + OFF_H);
    float*    dg   = (float*)   (ws + OFF_DG);
    int*      cnt  = (int*)     (ws + OFF_CNT);
    int*      offs = (int*)     (ws + OFF_OFFS);
    int*      cur  = (int*)     (ws + OFF_CUR);
    int*      bsrc = (int*)     (ws + OFF_BSRC);
    float*    bc   = (float*)   (ws + OFF_BC);
    ushort_t* WT   = (ushort_t*)(ws + OFF_WT);
    float*    coef = (float*)   (ws + OFF_COEF);
    int*      mode = (int*)     (ws + OFF_MODE);

    detect_k<<<1, 256, 0, stream>>>((const ushort_t*)x, mode);
    zero_k<<<(NN + 255) / 256, 256, 0, stream>>>(cnt);
    prep_w_k<<<64, 256, 0, stream>>>(Wx, gcnw, mode, WT);
    prep_c_k<<<1, 256, 0, stream>>>(wc, bb, thb, gam, bet, mea, var, linw, linb, mode, coef);
    degree_k<<<(NE + 255) / 256, 256, 0, stream>>>(ei, cnt);
    scan_k<<<1, SCAN_T, 0, stream>>>(cnt, offs, cur, dg);
    fill_k<<<(NE + 255) / 256, 256, 0, stream>>>(ei, dg, cur, bsrc, bc);
    gates_k<<<(NN + 63) / 64, 256, 0, stream>>>(x, WT, coef, mode, h);
    gat_out_k<<<(NN * 64 + 255) / 256, 256, 0, stream>>>(h, offs, cur, bsrc, bc, dg, gcnb, coef, mode, d_out);
}

// Round 5
// 286.272 us; speedup vs baseline: 2.7178x; 1.5090x over previous
//
#include <hip/hip_runtime.h>
#include <hip/hip_bf16.h>

// Problem constants (reference: N, E, K, F_IN, H = 50000, 640000, 3, 128, 128)
#define NN 50000
#define NE 640000
#define NP 196          // ceil(NN/256) partial-scan blocks

typedef unsigned short ushort_t;
typedef unsigned int uint_t;
typedef __attribute__((ext_vector_type(8))) short bf16x8;   // 8 bf16 = 4 VGPRs
typedef __attribute__((ext_vector_type(4))) float f32x4;

__device__ __forceinline__ float b2f(ushort_t u) {
    union { uint_t u; float f; } v; v.u = ((uint_t)u) << 16; return v.f;
}
__device__ __forceinline__ ushort_t f2b(float f) {
    union { float f; uint_t u; } v; v.f = f;
    uint_t u = v.u;
    uint_t r = u + 0x7fffu + ((u >> 16) & 1u);   // round-nearest-even
    return (ushort_t)(r >> 16);
}
__device__ __forceinline__ float sigf(float x) { return 1.0f / (1.0f + expf(-x)); }
// mode-aware scalar param load: mf=1 -> f32 array, mf=0 -> bf16 array
__device__ __forceinline__ float ldm(const void* p, int i, int mf) {
    return mf ? ((const float*)p)[i] : b2f(((const ushort_t*)p)[i]);
}

// ---- workspace layout (bytes), total 18.86 MB (known-good ceiling: 31.65 MB) ----
// hb   : NN*128 bf16 @ 0            (12,800,000)  post-gcn_w features
// dg   : NN f32      @ 12,800,000   (200,000)
// cnt  : NN i32      @ 13,000,000   (200,000)
// offs : NN i32      @ 13,200,000   (200,000)     CSR row start
// cur  : NN i32      @ 13,400,000   (200,000)     fill cursor; post-fill = row end
// bsc  : NE int2     @ 13,600,000   (5,120,000)   packed {src, dg[s]*dg[d] bits}
// part : NP i32      @ 18,720,000   (784)
// poff : NP i32      @ 18,720,784   (784)
// WT   : 4*16384 b16 @ 18,721,568   (131,072)     Wi^T, Wc^T, Wo^T, gcn_w^T ([f][k])
// coef : 641 f32     @ 18,852,640   (2,564)
// mode : i32         @ 18,855,208
#define OFF_HB   0
#define OFF_DG   12800000
#define OFF_CNT  13000000
#define OFF_OFFS 13200000
#define OFF_CUR  13400000
#define OFF_BSC  13600000
#define OFF_PART 18720000
#define OFF_POFF 18720784
#define OFF_WT   18721568
#define OFF_COEF 18852640
#define OFF_MODE 18855208
#define WS_REQ   18855216

__global__ void fb_k(ushort_t* __restrict__ out, int n) {   // ws too small: diagnostic zeros
    int i = blockIdx.x * blockDim.x + threadIdx.x;
    if (i < n) out[i] = 0;
}

// blocks 0..NP-1: zero cnt. block NP: dtype detect (f32-as-bf16 halves show
// huge exponents ~25% >= 0xC0; real bf16 N(0,1) never does).
__global__ void init_k(const ushort_t* __restrict__ x, int* __restrict__ cnt,
                       int* __restrict__ mode) {
    __shared__ int s[256];
    int b = blockIdx.x, t = threadIdx.x;
    if (b < NP) {
        int i = b * 256 + t;
        if (i < NN) cnt[i] = 0;
    } else {
        int bad = 0;
        for (int i = t; i < 4096; i += 256) {
            int e = (x[i] >> 7) & 0xFF;
            if (e >= 0xC0) bad++;
        }
        s[t] = bad; __syncthreads();
        for (int o = 128; o >= 1; o >>= 1) { if (t < o) s[t] += s[t + o]; __syncthreads(); }
        if (t == 0) mode[0] = (s[0] > 8) ? 1 : 0;   // 1 = f32 inputs, 0 = bf16
    }
}

// blocks 0..63: transpose W_x[0],W_x[2],W_x[3],gcn_w -> bf16 [f][k].
// block 64: fold biases (cheb(0)=theta_b), peephole w_c[2], relu->BN->linear tail.
__global__ void prep_k(const void* __restrict__ Wx, const void* __restrict__ gcnw,
                       const void* __restrict__ wc, const void* __restrict__ bb,
                       const void* __restrict__ thb,
                       const void* __restrict__ gam, const void* __restrict__ bet,
                       const void* __restrict__ mea, const void* __restrict__ var,
                       const void* __restrict__ linw, const void* __restrict__ linb,
                       const int* __restrict__ mode,
                       ushort_t* __restrict__ WT, float* __restrict__ coef) {
    __shared__ float red[128];
    int b = blockIdx.x, t = threadIdx.x;
    int mf = mode[0];
    if (b < 64) {
        int gid = b * 256 + t;
        int f = gid >> 7, k = gid & 127;
        const int srcoff[4] = { 0, 2 * 16384, 3 * 16384, 0 };
        #pragma unroll
        for (int m = 0; m < 4; m++) {
            const void* S = (m == 3) ? gcnw : Wx;
            WT[m * 16384 + gid] = f2b(ldm(S, srcoff[m] + k * 128 + f, mf));
        }
    } else {
        if (t < 128) {
            float rs = rsqrtf(ldm(var, t, mf) + 1e-5f);
            float ga = ldm(gam, t, mf);
            float lw = ldm(linw, t, mf);
            coef[t]       = ldm(thb, t, mf)           + ldm(bb, t, mf);            // bias_i
            coef[128 + t] = ldm(thb, 2 * 128 + t, mf) + ldm(bb, 2 * 128 + t, mf);  // bias_c
            coef[256 + t] = ldm(thb, 3 * 128 + t, mf) + ldm(bb, 3 * 128 + t, mf);  // bias_o
            coef[384 + t] = ldm(wc, 2 * 128 + t, mf);                              // w_c[2]
            coef[512 + t] = ga * rs * lw;                                          // s[f]
            red[t] = (ldm(bet, t, mf) - ldm(mea, t, mf) * ga * rs) * lw;
        }
        __syncthreads();
        for (int off = 64; off >= 1; off >>= 1) {
            if (t < off && t < 128) red[t] += red[t + off];
            __syncthreads();
        }
        if (t == 0) coef[640] = red[0] + ldm(linb, 0, mf);                         // C
    }
}

__global__ void degree_k(const int* __restrict__ ei, int* __restrict__ cnt) {
    int e = blockIdx.x * blockDim.x + threadIdx.x;
    if (e < NE) atomicAdd(&cnt[ei[NE + e]], 1);
}

// 3-pass parallel exclusive scan of cnt (R4's single-block scan_k was 134 us serial)
__global__ void part_k(const int* __restrict__ cnt, int* __restrict__ part) {
    __shared__ int s[256];
    int b = blockIdx.x, t = threadIdx.x, i = b * 256 + t;
    s[t] = (i < NN) ? cnt[i] : 0;
    __syncthreads();
    for (int o = 128; o >= 1; o >>= 1) { if (t < o) s[t] += s[t + o]; __syncthreads(); }
    if (t == 0) part[b] = s[0];
}

__global__ void scanpart_k(const int* __restrict__ part, int* __restrict__ poff) {
    __shared__ int s[256];
    int t = threadIdx.x;
    int v = (t < NP) ? part[t] : 0;
    s[t] = v; __syncthreads();
    for (int o = 1; o < 256; o <<= 1) {
        int u = (t >= o) ? s[t - o] : 0;
        __syncthreads();
        s[t] += u;
        __syncthreads();
    }
    if (t < NP) poff[t] = s[t] - v;   // exclusive
}

__global__ void emit_k(const int* __restrict__ cnt, const int* __restrict__ poff,
                       int* __restrict__ offs, int* __restrict__ cur, float* __restrict__ dg) {
    __shared__ int s[256];
    int b = blockIdx.x, t = threadIdx.x, i = b * 256 + t;
    int v = (i < NN) ? cnt[i] : 0;
    s[t] = v; __syncthreads();
    for (int o = 1; o < 256; o <<= 1) {
        int u = (t >= o) ? s[t - o] : 0;
        __syncthreads();
        s[t] += u;
        __syncthreads();
    }
    if (i < NN) {
        int excl = poff[b] + s[t] - v;
        offs[i] = excl;
        cur[i]  = excl;
        dg[i] = rsqrtf(1.0f + (float)(v < 0 ? 0 : v));
    }
}

// bucket edges by destination; one packed 8B store per edge (halves line-dirty
// write amplification vs two 4B stores to separate arrays: R4 showed 86 MB HBM)
__global__ void fill_k(const int* __restrict__ ei, const float* __restrict__ dg,
                       int* __restrict__ cur, int2* __restrict__ bsc) {
    int e = blockIdx.x * blockDim.x + threadIdx.x;
    if (e < NE) {
        int s = ei[e], d = ei[NE + e];
        int pos = atomicAdd(&cur[d], 1);
        int2 p; p.x = s; p.y = __float_as_int(dg[s] * dg[d]);
        bsc[pos] = p;
    }
}

// ---------------------------------------------------------------------------
// Fused gates + gcn GEMM -> hb (bf16). One block = 4 waves = 64 nodes; wave w
// owns LDS rows [16w,16w+16) in both stages. MFMA f32_16x16x32_bf16 layouts:
//   A: a[j]=A[m=lane&15][k=(lane>>4)*8+j];  B: b[j]=B[k=(lane>>4)*8+j][n=lane&15]
//   D: reg r -> row (lane>>4)*4+r, col lane&15
// ---------------------------------------------------------------------------
__launch_bounds__(256)
__global__ void gates_k(const void* __restrict__ x, const ushort_t* __restrict__ WT,
                        const float* __restrict__ coef, const int* __restrict__ mode,
                        ushort_t* __restrict__ hb) {
    __shared__ ushort_t tile[64 * 136];   // +8 pad: row stride 272B
    int t = threadIdx.x;
    int base = blockIdx.x * 64;
    int mf = mode[0];

    for (int i = 0; i < 4; i++) {
        int idx = (i * 256 + t) * 8;
        int row = idx >> 7, col = idx & 127;
        int n = base + row;
        bf16x8 v;
        if (n >= NN) {
            v = (bf16x8)0;
        } else if (mf == 0) {
            v = *(const bf16x8*)((const ushort_t*)x + n * 128 + col);
        } else {
            const float* xf = (const float*)x + n * 128 + col;
            float4 lo = *(const float4*)xf;
            float4 hi = *(const float4*)(xf + 4);
            v[0] = (short)f2b(lo.x); v[1] = (short)f2b(lo.y);
            v[2] = (short)f2b(lo.z); v[3] = (short)f2b(lo.w);
            v[4] = (short)f2b(hi.x); v[5] = (short)f2b(hi.y);
            v[6] = (short)f2b(hi.z); v[7] = (short)f2b(hi.w);
        }
        *(bf16x8*)&tile[row * 136 + col] = v;
    }
    __syncthreads();

    int lane = t & 63, wave = t >> 6;
    int m = lane & 15, quad = lane >> 4;
    int rowA = wave * 16 + m;

    bf16x8 a[4];
    #pragma unroll
    for (int kt = 0; kt < 4; kt++)
        a[kt] = *(const bf16x8*)&tile[rowA * 136 + kt * 32 + quad * 8];
    __syncthreads();   // all x reads done before Hs overwrites tile

    const ushort_t* WTi = WT;
    const ushort_t* WTc = WT + 16384;
    const ushort_t* WTo = WT + 2 * 16384;

    #pragma unroll
    for (int ft = 0; ft < 8; ft++) {
        int f = ft * 16 + m;
        f32x4 ai = {0,0,0,0}, ac = {0,0,0,0}, ao = {0,0,0,0};
        #pragma unroll
        for (int kt = 0; kt < 4; kt++) {
            int off = f * 128 + kt * 32 + quad * 8;
            bf16x8 bi  = *(const bf16x8*)(WTi + off);
            bf16x8 bc8 = *(const bf16x8*)(WTc + off);
            bf16x8 bo  = *(const bf16x8*)(WTo + off);
            ai = __builtin_amdgcn_mfma_f32_16x16x32_bf16(a[kt], bi,  ai, 0, 0, 0);
            ac = __builtin_amdgcn_mfma_f32_16x16x32_bf16(a[kt], bc8, ac, 0, 0, 0);
            ao = __builtin_amdgcn_mfma_f32_16x16x32_bf16(a[kt], bo,  ao, 0, 0, 0);
        }
        float bi_f = coef[f], bc_f = coef[128 + f], bo_f = coef[256 + f], w2 = coef[384 + f];
        #pragma unroll
        for (int r = 0; r < 4; r++) {
            float I  = sigf(ai[r] + bi_f);
            float T  = tanhf(ac[r] + bc_f);
            float Cs = I * T;                       // F*C_prev = 0
            float O  = sigf(ao[r] + w2 * Cs + bo_f);
            float Hs = O * tanhf(Cs);
            tile[(wave * 16 + quad * 4 + r) * 136 + f] = f2b(Hs);
        }
    }
    __syncthreads();   // Hs tile complete before stage-2 reads

    const ushort_t* WTg = WT + 3 * 16384;
    bf16x8 ah[4];
    #pragma unroll
    for (int kt = 0; kt < 4; kt++)
        ah[kt] = *(const bf16x8*)&tile[rowA * 136 + kt * 32 + quad * 8];

    #pragma unroll
    for (int ft = 0; ft < 8; ft++) {
        int f = ft * 16 + m;
        f32x4 acc = {0,0,0,0};
        #pragma unroll
        for (int kt = 0; kt < 4; kt++) {
            bf16x8 bg = *(const bf16x8*)(WTg + f * 128 + kt * 32 + quad * 8);
            acc = __builtin_amdgcn_mfma_f32_16x16x32_bf16(ah[kt], bg, acc, 0, 0, 0);
        }
        #pragma unroll
        for (int r = 0; r < 4; r++) {
            int n = base + wave * 16 + quad * 4 + r;
            if (n < NN) hb[n * 128 + f] = f2b(acc[r]);   // bf16: halves gather traffic
        }
    }
}

// ---------------------------------------------------------------------------
// Fused gather + self-loop + relu->BN->linear. One wave per destination node,
// 2 bf16 feats/lane (4B row slice), fp32 accumulation — zero atomics.
// ---------------------------------------------------------------------------
__launch_bounds__(256)
__global__ void gat_out_k(const ushort_t* __restrict__ hb, const int* __restrict__ offs,
                          const int* __restrict__ cur, const int2* __restrict__ bsc,
                          const float* __restrict__ dg,
                          const void* __restrict__ gcnb, const float* __restrict__ coef,
                          const int* __restrict__ mode, void* __restrict__ out) {
    int wid  = (blockIdx.x * blockDim.x + threadIdx.x) >> 6;
    int lane = threadIdx.x & 63;
    if (wid >= NN) return;
    int beg = offs[wid], end = cur[wid];   // cur post-fill == row end
    float a0 = 0.0f, a1 = 0.0f;
    int j = beg;
    for (; j + 1 < end; j += 2) {          // 2-way unroll: overlap the row loads
        int2 p0 = bsc[j], p1 = bsc[j + 1];
        uint_t r0 = *(const uint_t*)(hb + p0.x * 128 + lane * 2);
        uint_t r1 = *(const uint_t*)(hb + p1.x * 128 + lane * 2);
        float c0 = __int_as_float(p0.y), c1 = __int_as_float(p1.y);
        a0 += c0 * b2f((ushort_t)(r0 & 0xffffu)) + c1 * b2f((ushort_t)(r1 & 0xffffu));
        a1 += c0 * b2f((ushort_t)(r0 >> 16))     + c1 * b2f((ushort_t)(r1 >> 16));
    }
    if (j < end) {
        int2 p = bsc[j];
        uint_t r = *(const uint_t*)(hb + p.x * 128 + lane * 2);
        float c = __int_as_float(p.y);
        a0 += c * b2f((ushort_t)(r & 0xffffu));
        a1 += c * b2f((ushort_t)(r >> 16));
    }
    int mf = mode[0];
    uint_t rs = *(const uint_t*)(hb + wid * 128 + lane * 2);
    float d = dg[wid], d2 = d * d;
    float g0 = a0 + d2 * b2f((ushort_t)(rs & 0xffffu)) + ldm(gcnb, lane * 2,     mf);
    float g1 = a1 + d2 * b2f((ushort_t)(rs >> 16))     + ldm(gcnb, lane * 2 + 1, mf);
    float v = fmaxf(g0, 0.0f) * coef[512 + lane * 2]
            + fmaxf(g1, 0.0f) * coef[512 + lane * 2 + 1];
    #pragma unroll
    for (int o = 32; o >= 1; o >>= 1) v += __shfl_down(v, o);
    if (lane == 0) {
        float r = v + coef[640];
        if (mf) ((float*)out)[wid] = r;
        else    ((ushort_t*)out)[wid] = f2b(r);
    }
}

extern "C" void kernel_launch(void* const* d_in, const int* in_sizes, int n_in,
                              void* d_out, int out_size, void* d_ws, size_t ws_size,
                              hipStream_t stream) {
    if (ws_size < (size_t)WS_REQ) {   // diagnostic: finite 0.088 failure, not NaN
        fb_k<<<(out_size + 255) / 256, 256, 0, stream>>>((ushort_t*)d_out, out_size);
        return;
    }
    const void* x    = d_in[0];
    const int*  ei   = (const int*)d_in[1];
    // d_in[2] edge_weight: unused (ChebConv of zero state collapses to bias)
    const void* Wx   = d_in[3];
    const void* wc   = d_in[4];
    const void* bb   = d_in[5];
    // d_in[6] theta: unused
    const void* thb  = d_in[7];
    const void* gcnw = d_in[8];
    const void* gcnb = d_in[9];
    const void* gam  = d_in[10];
    const void* bet  = d_in[11];
    const void* mea  = d_in[12];
    const void* var  = d_in[13];
    const void* linw = d_in[14];
    const void* linb = d_in[15];

    char* ws = (char*)d_ws;
    ushort_t* hb   = (ushort_t*)(ws + OFF_HB);
    float*    dg   = (float*)   (ws + OFF_DG);
    int*      cnt  = (int*)     (ws + OFF_CNT);
    int*      offs = (int*)     (ws + OFF_OFFS);
    int*      cur  = (int*)     (ws + OFF_CUR);
    int2*     bsc  = (int2*)    (ws + OFF_BSC);
    int*      part = (int*)     (ws + OFF_PART);
    int*      poff = (int*)     (ws + OFF_POFF);
    ushort_t* WT   = (ushort_t*)(ws + OFF_WT);
    float*    coef = (float*)   (ws + OFF_COEF);
    int*      mode = (int*)     (ws + OFF_MODE);

    init_k<<<NP + 1, 256, 0, stream>>>((const ushort_t*)x, cnt, mode);
    prep_k<<<65, 256, 0, stream>>>(Wx, gcnw, wc, bb, thb, gam, bet, mea, var, linw, linb, mode, WT, coef);
    degree_k<<<(NE + 255) / 256, 256, 0, stream>>>(ei, cnt);
    part_k<<<NP, 256, 0, stream>>>(cnt, part);
    scanpart_k<<<1, 256, 0, stream>>>(part, poff);
    emit_k<<<NP, 256, 0, stream>>>(cnt, poff, offs, cur, dg);
    fill_k<<<(NE + 255) / 256, 256, 0, stream>>>(ei, dg, cur, bsc);
    gates_k<<<(NN + 63) / 64, 256, 0, stream>>>(x, WT, coef, mode, hb);
    gat_out_k<<<(NN * 64 + 255) / 256, 256, 0, stream>>>(hb, offs, cur, bsc, dg, gcnb, coef, mode, d_out);
}

// Round 6
// 248.154 us; speedup vs baseline: 3.1352x; 1.1536x over previous
//
#include <hip/hip_runtime.h>
#include <hip/hip_bf16.h>

// Problem constants (reference: N, E, K, F_IN, H = 50000, 640000, 3, 128, 128)
#define NN 50000
#define NE 640000
#define NP 196          // ceil(NN/256) partial-scan blocks

typedef unsigned short ushort_t;
typedef unsigned int uint_t;
typedef __attribute__((ext_vector_type(8))) short bf16x8;   // 8 bf16 = 4 VGPRs
typedef __attribute__((ext_vector_type(4))) float f32x4;

__device__ __forceinline__ float b2f(ushort_t u) {
    union { uint_t u; float f; } v; v.u = ((uint_t)u) << 16; return v.f;
}
__device__ __forceinline__ ushort_t f2b(float f) {
    union { float f; uint_t u; } v; v.f = f;
    uint_t u = v.u;
    uint_t r = u + 0x7fffu + ((u >> 16) & 1u);   // round-nearest-even
    return (ushort_t)(r >> 16);
}
// fast transcendentals: v_exp + v_rcp (err ~1e-6, vs 4.9e-4 pipeline absmax)
__device__ __forceinline__ float fsig(float x)  { return __builtin_amdgcn_rcpf(1.0f + __expf(-x)); }
__device__ __forceinline__ float ftanh(float x) { return 1.0f - 2.0f * __builtin_amdgcn_rcpf(1.0f + __expf(2.0f * x)); }
// mode-aware scalar param load: mf=1 -> f32 array, mf=0 -> bf16 array
__device__ __forceinline__ float ldm(const void* p, int i, int mf) {
    return mf ? ((const float*)p)[i] : b2f(((const ushort_t*)p)[i]);
}

// ---- workspace layout (bytes), total 18.86 MB (known-good ceiling: 31.65 MB) ----
#define OFF_HB   0            // NN*128 bf16 (12,800,000)  post-gcn_w features
#define OFF_DG   12800000     // NN f32
#define OFF_CNT  13000000     // NN i32
#define OFF_OFFS 13200000     // NN i32   CSR row start
#define OFF_CUR  13400000     // NN i32   fill cursor; post-fill = row end
#define OFF_BSC  13600000     // NE int2  packed {src, dg[s]*dg[d] bits}
#define OFF_PART 18720000     // NP i32
#define OFF_POFF 18720784     // NP i32
#define OFF_WT   18721568     // 4*16384 bf16: Wi^T, Wc^T, Wo^T, gcn_w^T ([f][k])
#define OFF_COEF 18852640     // 641 f32
#define OFF_MODE 18855208     // i32
#define WS_REQ   18855216

__global__ void fb_k(ushort_t* __restrict__ out, int n) {   // ws too small: diagnostic zeros
    int i = blockIdx.x * blockDim.x + threadIdx.x;
    if (i < n) out[i] = 0;
}

// blocks 0..NP-1: zero cnt. block NP: dtype detect (f32-as-bf16 halves show
// huge exponents ~25% >= 0xC0; real bf16 N(0,1) never does).
__global__ void init_k(const ushort_t* __restrict__ x, int* __restrict__ cnt,
                       int* __restrict__ mode) {
    __shared__ int s[256];
    int b = blockIdx.x, t = threadIdx.x;
    if (b < NP) {
        int i = b * 256 + t;
        if (i < NN) cnt[i] = 0;
    } else {
        int bad = 0;
        for (int i = t; i < 4096; i += 256) {
            int e = (x[i] >> 7) & 0xFF;
            if (e >= 0xC0) bad++;
        }
        s[t] = bad; __syncthreads();
        for (int o = 128; o >= 1; o >>= 1) { if (t < o) s[t] += s[t + o]; __syncthreads(); }
        if (t == 0) mode[0] = (s[0] > 8) ? 1 : 0;   // 1 = f32 inputs, 0 = bf16
    }
}

// blocks 0..63: transpose W_x[0],W_x[2],W_x[3],gcn_w -> bf16 [f][k].
// block 64: fold biases (cheb(0)=theta_b), peephole w_c[2], relu->BN->linear tail.
__global__ void prep_k(const void* __restrict__ Wx, const void* __restrict__ gcnw,
                       const void* __restrict__ wc, const void* __restrict__ bb,
                       const void* __restrict__ thb,
                       const void* __restrict__ gam, const void* __restrict__ bet,
                       const void* __restrict__ mea, const void* __restrict__ var,
                       const void* __restrict__ linw, const void* __restrict__ linb,
                       const int* __restrict__ mode,
                       ushort_t* __restrict__ WT, float* __restrict__ coef) {
    __shared__ float red[128];
    int b = blockIdx.x, t = threadIdx.x;
    int mf = mode[0];
    if (b < 64) {
        int gid = b * 256 + t;
        int f = gid >> 7, k = gid & 127;
        const int srcoff[4] = { 0, 2 * 16384, 3 * 16384, 0 };
        #pragma unroll
        for (int m = 0; m < 4; m++) {
            const void* S = (m == 3) ? gcnw : Wx;
            WT[m * 16384 + gid] = f2b(ldm(S, srcoff[m] + k * 128 + f, mf));
        }
    } else {
        if (t < 128) {
            float rs = rsqrtf(ldm(var, t, mf) + 1e-5f);
            float ga = ldm(gam, t, mf);
            float lw = ldm(linw, t, mf);
            coef[t]       = ldm(thb, t, mf)           + ldm(bb, t, mf);            // bias_i
            coef[128 + t] = ldm(thb, 2 * 128 + t, mf) + ldm(bb, 2 * 128 + t, mf);  // bias_c
            coef[256 + t] = ldm(thb, 3 * 128 + t, mf) + ldm(bb, 3 * 128 + t, mf);  // bias_o
            coef[384 + t] = ldm(wc, 2 * 128 + t, mf);                              // w_c[2]
            coef[512 + t] = ga * rs * lw;                                          // s[f]
            red[t] = (ldm(bet, t, mf) - ldm(mea, t, mf) * ga * rs) * lw;
        }
        __syncthreads();
        for (int off = 64; off >= 1; off >>= 1) {
            if (t < off && t < 128) red[t] += red[t + off];
            __syncthreads();
        }
        if (t == 0) coef[640] = red[0] + ldm(linb, 0, mf);                         // C
    }
}

__global__ void degree_k(const int* __restrict__ ei, int* __restrict__ cnt) {
    int e = blockIdx.x * blockDim.x + threadIdx.x;
    if (e < NE) atomicAdd(&cnt[ei[NE + e]], 1);
}

// 3-pass parallel exclusive scan of cnt
__global__ void part_k(const int* __restrict__ cnt, int* __restrict__ part) {
    __shared__ int s[256];
    int b = blockIdx.x, t = threadIdx.x, i = b * 256 + t;
    s[t] = (i < NN) ? cnt[i] : 0;
    __syncthreads();
    for (int o = 128; o >= 1; o >>= 1) { if (t < o) s[t] += s[t + o]; __syncthreads(); }
    if (t == 0) part[b] = s[0];
}

__global__ void scanpart_k(const int* __restrict__ part, int* __restrict__ poff) {
    __shared__ int s[256];
    int t = threadIdx.x;
    int v = (t < NP) ? part[t] : 0;
    s[t] = v; __syncthreads();
    for (int o = 1; o < 256; o <<= 1) {
        int u = (t >= o) ? s[t - o] : 0;
        __syncthreads();
        s[t] += u;
        __syncthreads();
    }
    if (t < NP) poff[t] = s[t] - v;   // exclusive
}

__global__ void emit_k(const int* __restrict__ cnt, const int* __restrict__ poff,
                       int* __restrict__ offs, int* __restrict__ cur, float* __restrict__ dg) {
    __shared__ int s[256];
    int b = blockIdx.x, t = threadIdx.x, i = b * 256 + t;
    int v = (i < NN) ? cnt[i] : 0;
    s[t] = v; __syncthreads();
    for (int o = 1; o < 256; o <<= 1) {
        int u = (t >= o) ? s[t - o] : 0;
        __syncthreads();
        s[t] += u;
        __syncthreads();
    }
    if (i < NN) {
        int excl = poff[b] + s[t] - v;
        offs[i] = excl;
        cur[i]  = excl;
        dg[i] = rsqrtf(1.0f + (float)(v < 0 ? 0 : v));
    }
}

// bucket edges by destination; one packed 8B store per edge
__global__ void fill_k(const int* __restrict__ ei, const float* __restrict__ dg,
                       int* __restrict__ cur, int2* __restrict__ bsc) {
    int e = blockIdx.x * blockDim.x + threadIdx.x;
    if (e < NE) {
        int s = ei[e], d = ei[NE + e];
        int pos = atomicAdd(&cur[d], 1);
        int2 p; p.x = s; p.y = __float_as_int(dg[s] * dg[d]);
        bsc[pos] = p;
    }
}

// ---------------------------------------------------------------------------
// Fused gates + gcn GEMM -> hb (bf16). One block = 4 waves = 64 nodes.
// R5 repartition: wave w owns FEATURE columns [32w, 32w+32) for ALL 64 rows
// (R4's row-strip split made every wave load the whole 32KB weight matrix ->
// 4x redundant global traffic, VGPR 56, load-latency-bound, MfmaUtil 2.7%).
// Now B-frags load once into registers and are reused over 4 row tiles.
// MFMA f32_16x16x32_bf16 layouts (HW-verified):
//   A: a[j]=A[m=lane&15][k=(lane>>4)*8+j];  B: b[j]=B[k=(lane>>4)*8+j][n=lane&15]
//   D: reg r -> row (lane>>4)*4+r, col lane&15
// ---------------------------------------------------------------------------
__launch_bounds__(256)
__global__ void gates_k(const void* __restrict__ x, const ushort_t* __restrict__ WT,
                        const float* __restrict__ coef, const int* __restrict__ mode,
                        ushort_t* __restrict__ hb) {
    __shared__ ushort_t tile[64 * 136];   // +8 pad: row stride 272B
    int t = threadIdx.x;
    int base = blockIdx.x * 64;
    int mf = mode[0];

    for (int i = 0; i < 4; i++) {
        int idx = (i * 256 + t) * 8;
        int row = idx >> 7, col = idx & 127;
        int n = base + row;
        bf16x8 v;
        if (n >= NN) {
            v = (bf16x8)0;
        } else if (mf == 0) {
            v = *(const bf16x8*)((const ushort_t*)x + n * 128 + col);
        } else {
            const float* xf = (const float*)x + n * 128 + col;
            float4 lo = *(const float4*)xf;
            float4 hi = *(const float4*)(xf + 4);
            v[0] = (short)f2b(lo.x); v[1] = (short)f2b(lo.y);
            v[2] = (short)f2b(lo.z); v[3] = (short)f2b(lo.w);
            v[4] = (short)f2b(hi.x); v[5] = (short)f2b(hi.y);
            v[6] = (short)f2b(hi.z); v[7] = (short)f2b(hi.w);
        }
        *(bf16x8*)&tile[row * 136 + col] = v;
    }
    __syncthreads();

    int lane = t & 63, wave = t >> 6;
    int m = lane & 15, quad = lane >> 4;

    // A-frags for all 4 row-tiles x 4 k-tiles (LDS, reused by both f-tiles)
    bf16x8 a[4][4];
    #pragma unroll
    for (int rt = 0; rt < 4; rt++)
        #pragma unroll
        for (int kt = 0; kt < 4; kt++)
            a[rt][kt] = *(const bf16x8*)&tile[(rt * 16 + m) * 136 + kt * 32 + quad * 8];
    __syncthreads();   // all x reads done before Hs overwrites tile

    const ushort_t* WTi = WT;
    const ushort_t* WTc = WT + 16384;
    const ushort_t* WTo = WT + 2 * 16384;

    #pragma unroll
    for (int ft = 0; ft < 2; ft++) {
        int f = wave * 32 + ft * 16 + m;
        // B-frags: loaded ONCE, reused across 4 row tiles (12 x 16B per lane)
        bf16x8 bi[4], bc[4], bo[4];
        #pragma unroll
        for (int kt = 0; kt < 4; kt++) {
            int off = f * 128 + kt * 32 + quad * 8;
            bi[kt] = *(const bf16x8*)(WTi + off);
            bc[kt] = *(const bf16x8*)(WTc + off);
            bo[kt] = *(const bf16x8*)(WTo + off);
        }
        float bi_f = coef[f], bc_f = coef[128 + f], bo_f = coef[256 + f], w2 = coef[384 + f];
        #pragma unroll
        for (int rt = 0; rt < 4; rt++) {
            f32x4 ai = {0,0,0,0}, ac = {0,0,0,0}, ao = {0,0,0,0};
            #pragma unroll
            for (int kt = 0; kt < 4; kt++) {
                ai = __builtin_amdgcn_mfma_f32_16x16x32_bf16(a[rt][kt], bi[kt], ai, 0, 0, 0);
                ac = __builtin_amdgcn_mfma_f32_16x16x32_bf16(a[rt][kt], bc[kt], ac, 0, 0, 0);
                ao = __builtin_amdgcn_mfma_f32_16x16x32_bf16(a[rt][kt], bo[kt], ao, 0, 0, 0);
            }
            #pragma unroll
            for (int r = 0; r < 4; r++) {
                float I  = fsig(ai[r] + bi_f);
                float T  = ftanh(ac[r] + bc_f);
                float Cs = I * T;                       // F*C_prev = 0
                float O  = fsig(ao[r] + w2 * Cs + bo_f);
                float Hs = O * ftanh(Cs);
                tile[(rt * 16 + quad * 4 + r) * 136 + f] = f2b(Hs);
            }
        }
    }
    __syncthreads();   // Hs tile complete (col-partitioned across waves)

    const ushort_t* WTg = WT + 3 * 16384;
    bf16x8 ah[4][4];
    #pragma unroll
    for (int rt = 0; rt < 4; rt++)
        #pragma unroll
        for (int kt = 0; kt < 4; kt++)
            ah[rt][kt] = *(const bf16x8*)&tile[(rt * 16 + m) * 136 + kt * 32 + quad * 8];

    #pragma unroll
    for (int ft = 0; ft < 2; ft++) {
        int f = wave * 32 + ft * 16 + m;
        bf16x8 bg[4];
        #pragma unroll
        for (int kt = 0; kt < 4; kt++)
            bg[kt] = *(const bf16x8*)(WTg + f * 128 + kt * 32 + quad * 8);
        #pragma unroll
        for (int rt = 0; rt < 4; rt++) {
            f32x4 acc = {0,0,0,0};
            #pragma unroll
            for (int kt = 0; kt < 4; kt++)
                acc = __builtin_amdgcn_mfma_f32_16x16x32_bf16(ah[rt][kt], bg[kt], acc, 0, 0, 0);
            #pragma unroll
            for (int r = 0; r < 4; r++) {
                int n = base + rt * 16 + quad * 4 + r;
                if (n < NN) hb[n * 128 + f] = f2b(acc[r]);   // bf16: halves gather traffic
            }
        }
    }
}

// ---------------------------------------------------------------------------
// Fused gather + self-loop + relu->BN->linear. One wave per destination node,
// 2 bf16 feats/lane (4B row slice), fp32 accumulation — zero atomics.
// ---------------------------------------------------------------------------
__launch_bounds__(256)
__global__ void gat_out_k(const ushort_t* __restrict__ hb, const int* __restrict__ offs,
                          const int* __restrict__ cur, const int2* __restrict__ bsc,
                          const float* __restrict__ dg,
                          const void* __restrict__ gcnb, const float* __restrict__ coef,
                          const int* __restrict__ mode, void* __restrict__ out) {
    int wid  = (blockIdx.x * blockDim.x + threadIdx.x) >> 6;
    int lane = threadIdx.x & 63;
    if (wid >= NN) return;
    int beg = offs[wid], end = cur[wid];   // cur post-fill == row end
    float a0 = 0.0f, a1 = 0.0f;
    int j = beg;
    for (; j + 1 < end; j += 2) {          // 2-way unroll: overlap the row loads
        int2 p0 = bsc[j], p1 = bsc[j + 1];
        uint_t r0 = *(const uint_t*)(hb + p0.x * 128 + lane * 2);
        uint_t r1 = *(const uint_t*)(hb + p1.x * 128 + lane * 2);
        float c0 = __int_as_float(p0.y), c1 = __int_as_float(p1.y);
        a0 += c0 * b2f((ushort_t)(r0 & 0xffffu)) + c1 * b2f((ushort_t)(r1 & 0xffffu));
        a1 += c0 * b2f((ushort_t)(r0 >> 16))     + c1 * b2f((ushort_t)(r1 >> 16));
    }
    if (j < end) {
        int2 p = bsc[j];
        uint_t r = *(const uint_t*)(hb + p.x * 128 + lane * 2);
        float c = __int_as_float(p.y);
        a0 += c * b2f((ushort_t)(r & 0xffffu));
        a1 += c * b2f((ushort_t)(r >> 16));
    }
    int mf = mode[0];
    uint_t rs = *(const uint_t*)(hb + wid * 128 + lane * 2);
    float d = dg[wid], d2 = d * d;
    float g0 = a0 + d2 * b2f((ushort_t)(rs & 0xffffu)) + ldm(gcnb, lane * 2,     mf);
    float g1 = a1 + d2 * b2f((ushort_t)(rs >> 16))     + ldm(gcnb, lane * 2 + 1, mf);
    float v = fmaxf(g0, 0.0f) * coef[512 + lane * 2]
            + fmaxf(g1, 0.0f) * coef[512 + lane * 2 + 1];
    #pragma unroll
    for (int o = 32; o >= 1; o >>= 1) v += __shfl_down(v, o);
    if (lane == 0) {
        float r = v + coef[640];
        if (mf) ((float*)out)[wid] = r;
        else    ((ushort_t*)out)[wid] = f2b(r);
    }
}

extern "C" void kernel_launch(void* const* d_in, const int* in_sizes, int n_in,
                              void* d_out, int out_size, void* d_ws, size_t ws_size,
                              hipStream_t stream) {
    if (ws_size < (size_t)WS_REQ) {   // diagnostic: finite 0.088 failure, not NaN
        fb_k<<<(out_size + 255) / 256, 256, 0, stream>>>((ushort_t*)d_out, out_size);
        return;
    }
    const void* x    = d_in[0];
    const int*  ei   = (const int*)d_in[1];
    // d_in[2] edge_weight: unused (ChebConv of zero state collapses to bias)
    const void* Wx   = d_in[3];
    const void* wc   = d_in[4];
    const void* bb   = d_in[5];
    // d_in[6] theta: unused
    const void* thb  = d_in[7];
    const void* gcnw = d_in[8];
    const void* gcnb = d_in[9];
    const void* gam  = d_in[10];
    const void* bet  = d_in[11];
    const void* mea  = d_in[12];
    const void* var  = d_in[13];
    const void* linw = d_in[14];
    const void* linb = d_in[15];

    char* ws = (char*)d_ws;
    ushort_t* hb   = (ushort_t*)(ws + OFF_HB);
    float*    dg   = (float*)   (ws + OFF_DG);
    int*      cnt  = (int*)     (ws + OFF_CNT);
    int*      offs = (int*)     (ws + OFF_OFFS);
    int*      cur  = (int*)     (ws + OFF_CUR);
    int2*     bsc  = (int2*)    (ws + OFF_BSC);
    int*      part = (int*)     (ws + OFF_PART);
    int*      poff = (int*)     (ws + OFF_POFF);
    ushort_t* WT   = (ushort_t*)(ws + OFF_WT);
    float*    coef = (float*)   (ws + OFF_COEF);
    int*      mode = (int*)     (ws + OFF_MODE);

    init_k<<<NP + 1, 256, 0, stream>>>((const ushort_t*)x, cnt, mode);
    prep_k<<<65, 256, 0, stream>>>(Wx, gcnw, wc, bb, thb, gam, bet, mea, var, linw, linb, mode, WT, coef);
    degree_k<<<(NE + 255) / 256, 256, 0, stream>>>(ei, cnt);
    part_k<<<NP, 256, 0, stream>>>(cnt, part);
    scanpart_k<<<1, 256, 0, stream>>>(part, poff);
    emit_k<<<NP, 256, 0, stream>>>(cnt, poff, offs, cur, dg);
    fill_k<<<(NE + 255) / 256, 256, 0, stream>>>(ei, dg, cur, bsc);
    gates_k<<<(NN + 63) / 64, 256, 0, stream>>>(x, WT, coef, mode, hb);
    gat_out_k<<<(NN * 64 + 255) / 256, 256, 0, stream>>>(hb, offs, cur, bsc, dg, gcnb, coef, mode, d_out);
}

// Round 7
// 235.830 us; speedup vs baseline: 3.2991x; 1.0523x over previous
//
#include <hip/hip_runtime.h>
#include <hip/hip_bf16.h>

// Problem constants (reference: N, E, K, F_IN, H = 50000, 640000, 3, 128, 128)
#define NN 50000
#define NE 640000
#define NP 196          // ceil(NN/256) partial-scan blocks

typedef unsigned short ushort_t;
typedef unsigned int uint_t;
typedef __attribute__((ext_vector_type(8))) short bf16x8;   // 8 bf16 = 4 VGPRs
typedef __attribute__((ext_vector_type(4))) float f32x4;

__device__ __forceinline__ float b2f(ushort_t u) {
    union { uint_t u; float f; } v; v.u = ((uint_t)u) << 16; return v.f;
}
__device__ __forceinline__ ushort_t f2b(float f) {
    union { float f; uint_t u; } v; v.f = f;
    uint_t u = v.u;
    uint_t r = u + 0x7fffu + ((u >> 16) & 1u);   // round-nearest-even
    return (ushort_t)(r >> 16);
}
// fast transcendentals: v_exp + v_rcp (err ~1e-6, vs 4.9e-4 pipeline absmax)
__device__ __forceinline__ float fsig(float x)  { return __builtin_amdgcn_rcpf(1.0f + __expf(-x)); }
__device__ __forceinline__ float ftanh(float x) { return 1.0f - 2.0f * __builtin_amdgcn_rcpf(1.0f + __expf(2.0f * x)); }
// mode-aware scalar param load: mf=1 -> f32 array, mf=0 -> bf16 array
__device__ __forceinline__ float ldm(const void* p, int i, int mf) {
    return mf ? ((const float*)p)[i] : b2f(((const ushort_t*)p)[i]);
}

// ---- workspace layout (bytes), total 16.3 MB ----
#define OFF_HB   0            // NN*128 bf16 (12,800,000)  dg[n]*h[n] pre-scaled
#define OFF_DG   12800000     // NN f32
#define OFF_CNT  13000000     // NN i32
#define OFF_OFFS 13200000     // NN i32   CSR row start
#define OFF_CUR  13400000     // NN i32   fill cursor; post-fill = row end
#define OFF_BSRC 13600000     // NE i32   bucketed src index (R7: no coef array)
#define OFF_PART 16160000     // NP i32
#define OFF_POFF 16160784     // NP i32
#define OFF_WT   16161568     // 4*16384 bf16: Wi^T, Wc^T, Wo^T, gcn_w^T ([f][k])
#define OFF_COEF 16292640     // 641 f32
#define OFF_MODE 16295208     // i32
#define WS_REQ   16295216

__global__ void fb_k(ushort_t* __restrict__ out, int n) {   // ws too small: diagnostic zeros
    int i = blockIdx.x * blockDim.x + threadIdx.x;
    if (i < n) out[i] = 0;
}

// blocks 0..NP-1: zero cnt. block NP: dtype detect (f32-as-bf16 halves show
// huge exponents ~25% >= 0xC0; real bf16 N(0,1) never does).
__global__ void init_k(const ushort_t* __restrict__ x, int* __restrict__ cnt,
                       int* __restrict__ mode) {
    __shared__ int s[256];
    int b = blockIdx.x, t = threadIdx.x;
    if (b < NP) {
        int i = b * 256 + t;
        if (i < NN) cnt[i] = 0;
    } else {
        int bad = 0;
        for (int i = t; i < 4096; i += 256) {
            int e = (x[i] >> 7) & 0xFF;
            if (e >= 0xC0) bad++;
        }
        s[t] = bad; __syncthreads();
        for (int o = 128; o >= 1; o >>= 1) { if (t < o) s[t] += s[t + o]; __syncthreads(); }
        if (t == 0) mode[0] = (s[0] > 8) ? 1 : 0;   // 1 = f32 inputs, 0 = bf16
    }
}

// blocks 0..63: transpose W_x[0],W_x[2],W_x[3],gcn_w -> bf16 [f][k].
// block 64: fold biases (cheb(0)=theta_b), peephole w_c[2], relu->BN->linear tail.
__global__ void prep_k(const void* __restrict__ Wx, const void* __restrict__ gcnw,
                       const void* __restrict__ wc, const void* __restrict__ bb,
                       const void* __restrict__ thb,
                       const void* __restrict__ gam, const void* __restrict__ bet,
                       const void* __restrict__ mea, const void* __restrict__ var,
                       const void* __restrict__ linw, const void* __restrict__ linb,
                       const int* __restrict__ mode,
                       ushort_t* __restrict__ WT, float* __restrict__ coef) {
    __shared__ float red[128];
    int b = blockIdx.x, t = threadIdx.x;
    int mf = mode[0];
    if (b < 64) {
        int gid = b * 256 + t;
        int f = gid >> 7, k = gid & 127;
        const int srcoff[4] = { 0, 2 * 16384, 3 * 16384, 0 };
        #pragma unroll
        for (int m = 0; m < 4; m++) {
            const void* S = (m == 3) ? gcnw : Wx;
            WT[m * 16384 + gid] = f2b(ldm(S, srcoff[m] + k * 128 + f, mf));
        }
    } else {
        if (t < 128) {
            float rs = rsqrtf(ldm(var, t, mf) + 1e-5f);
            float ga = ldm(gam, t, mf);
            float lw = ldm(linw, t, mf);
            coef[t]       = ldm(thb, t, mf)           + ldm(bb, t, mf);            // bias_i
            coef[128 + t] = ldm(thb, 2 * 128 + t, mf) + ldm(bb, 2 * 128 + t, mf);  // bias_c
            coef[256 + t] = ldm(thb, 3 * 128 + t, mf) + ldm(bb, 3 * 128 + t, mf);  // bias_o
            coef[384 + t] = ldm(wc, 2 * 128 + t, mf);                              // w_c[2]
            coef[512 + t] = ga * rs * lw;                                          // s[f]
            red[t] = (ldm(bet, t, mf) - ldm(mea, t, mf) * ga * rs) * lw;
        }
        __syncthreads();
        for (int off = 64; off >= 1; off >>= 1) {
            if (t < off && t < 128) red[t] += red[t + off];
            __syncthreads();
        }
        if (t == 0) coef[640] = red[0] + ldm(linb, 0, mf);                         // C
    }
}

__global__ void degree_k(const int* __restrict__ ei, int* __restrict__ cnt) {
    int e = blockIdx.x * blockDim.x + threadIdx.x;
    if (e < NE) atomicAdd(&cnt[ei[NE + e]], 1);
}

// 3-pass parallel exclusive scan of cnt
__global__ void part_k(const int* __restrict__ cnt, int* __restrict__ part) {
    __shared__ int s[256];
    int b = blockIdx.x, t = threadIdx.x, i = b * 256 + t;
    s[t] = (i < NN) ? cnt[i] : 0;
    __syncthreads();
    for (int o = 128; o >= 1; o >>= 1) { if (t < o) s[t] += s[t + o]; __syncthreads(); }
    if (t == 0) part[b] = s[0];
}

__global__ void scanpart_k(const int* __restrict__ part, int* __restrict__ poff) {
    __shared__ int s[256];
    int t = threadIdx.x;
    int v = (t < NP) ? part[t] : 0;
    s[t] = v; __syncthreads();
    for (int o = 1; o < 256; o <<= 1) {
        int u = (t >= o) ? s[t - o] : 0;
        __syncthreads();
        s[t] += u;
        __syncthreads();
    }
    if (t < NP) poff[t] = s[t] - v;   // exclusive
}

__global__ void emit_k(const int* __restrict__ cnt, const int* __restrict__ poff,
                       int* __restrict__ offs, int* __restrict__ cur, float* __restrict__ dg) {
    __shared__ int s[256];
    int b = blockIdx.x, t = threadIdx.x, i = b * 256 + t;
    int v = (i < NN) ? cnt[i] : 0;
    s[t] = v; __syncthreads();
    for (int o = 1; o < 256; o <<= 1) {
        int u = (t >= o) ? s[t - o] : 0;
        __syncthreads();
        s[t] += u;
        __syncthreads();
    }
    if (i < NN) {
        int excl = poff[b] + s[t] - v;
        offs[i] = excl;
        cur[i]  = excl;
        dg[i] = rsqrtf(1.0f + (float)(v < 0 ? 0 : v));
    }
}

// bucket edges by destination; 4B src only (coef folded into hb pre-scale)
__global__ void fill_k(const int* __restrict__ ei, int* __restrict__ cur,
                       int* __restrict__ bsrc) {
    int e = blockIdx.x * blockDim.x + threadIdx.x;
    if (e < NE) {
        int s = ei[e], d = ei[NE + e];
        int pos = atomicAdd(&cur[d], 1);
        bsrc[pos] = s;
    }
}

// ---------------------------------------------------------------------------
// Fused gates + gcn GEMM -> hb = dg[n]*h[n] (bf16). One block = 4 waves =
// 64 nodes; wave w owns feature cols [32w,32w+32) for all rows (B-frags load
// once, reuse over 4 row tiles). MFMA f32_16x16x32_bf16 layouts (HW-verified):
//   A: a[j]=A[m=lane&15][k=(lane>>4)*8+j];  B: b[j]=B[k=(lane>>4)*8+j][n=lane&15]
//   D: reg r -> row (lane>>4)*4+r, col lane&15
// ---------------------------------------------------------------------------
__launch_bounds__(256)
__global__ void gates_k(const void* __restrict__ x, const ushort_t* __restrict__ WT,
                        const float* __restrict__ coef, const float* __restrict__ dg,
                        const int* __restrict__ mode, ushort_t* __restrict__ hb) {
    __shared__ ushort_t tile[64 * 136];   // +8 pad: row stride 272B
    __shared__ float ldsdg[64];
    int t = threadIdx.x;
    int base = blockIdx.x * 64;
    int mf = mode[0];

    if (t < 64) {
        int n = base + t;
        ldsdg[t] = (n < NN) ? dg[n] : 0.0f;
    }
    for (int i = 0; i < 4; i++) {
        int idx = (i * 256 + t) * 8;
        int row = idx >> 7, col = idx & 127;
        int n = base + row;
        bf16x8 v;
        if (n >= NN) {
            v = (bf16x8)0;
        } else if (mf == 0) {
            v = *(const bf16x8*)((const ushort_t*)x + n * 128 + col);
        } else {
            const float* xf = (const float*)x + n * 128 + col;
            float4 lo = *(const float4*)xf;
            float4 hi = *(const float4*)(xf + 4);
            v[0] = (short)f2b(lo.x); v[1] = (short)f2b(lo.y);
            v[2] = (short)f2b(lo.z); v[3] = (short)f2b(lo.w);
            v[4] = (short)f2b(hi.x); v[5] = (short)f2b(hi.y);
            v[6] = (short)f2b(hi.z); v[7] = (short)f2b(hi.w);
        }
        *(bf16x8*)&tile[row * 136 + col] = v;
    }
    __syncthreads();

    int lane = t & 63, wave = t >> 6;
    int m = lane & 15, quad = lane >> 4;

    // A-frags for all 4 row-tiles x 4 k-tiles (LDS, reused by both f-tiles)
    bf16x8 a[4][4];
    #pragma unroll
    for (int rt = 0; rt < 4; rt++)
        #pragma unroll
        for (int kt = 0; kt < 4; kt++)
            a[rt][kt] = *(const bf16x8*)&tile[(rt * 16 + m) * 136 + kt * 32 + quad * 8];
    __syncthreads();   // all x reads done before Hs overwrites tile

    const ushort_t* WTi = WT;
    const ushort_t* WTc = WT + 16384;
    const ushort_t* WTo = WT + 2 * 16384;

    #pragma unroll
    for (int ft = 0; ft < 2; ft++) {
        int f = wave * 32 + ft * 16 + m;
        // B-frags: loaded ONCE, reused across 4 row tiles
        bf16x8 bi[4], bc[4], bo[4];
        #pragma unroll
        for (int kt = 0; kt < 4; kt++) {
            int off = f * 128 + kt * 32 + quad * 8;
            bi[kt] = *(const bf16x8*)(WTi + off);
            bc[kt] = *(const bf16x8*)(WTc + off);
            bo[kt] = *(const bf16x8*)(WTo + off);
        }
        float bi_f = coef[f], bc_f = coef[128 + f], bo_f = coef[256 + f], w2 = coef[384 + f];
        #pragma unroll
        for (int rt = 0; rt < 4; rt++) {
            f32x4 ai = {0,0,0,0}, ac = {0,0,0,0}, ao = {0,0,0,0};
            #pragma unroll
            for (int kt = 0; kt < 4; kt++) {
                ai = __builtin_amdgcn_mfma_f32_16x16x32_bf16(a[rt][kt], bi[kt], ai, 0, 0, 0);
                ac = __builtin_amdgcn_mfma_f32_16x16x32_bf16(a[rt][kt], bc[kt], ac, 0, 0, 0);
                ao = __builtin_amdgcn_mfma_f32_16x16x32_bf16(a[rt][kt], bo[kt], ao, 0, 0, 0);
            }
            #pragma unroll
            for (int r = 0; r < 4; r++) {
                float I  = fsig(ai[r] + bi_f);
                float T  = ftanh(ac[r] + bc_f);
                float Cs = I * T;                       // F*C_prev = 0
                float O  = fsig(ao[r] + w2 * Cs + bo_f);
                float Hs = O * ftanh(Cs);
                tile[(rt * 16 + quad * 4 + r) * 136 + f] = f2b(Hs);
            }
        }
    }
    __syncthreads();   // Hs tile complete (col-partitioned across waves)

    const ushort_t* WTg = WT + 3 * 16384;
    bf16x8 ah[4][4];
    #pragma unroll
    for (int rt = 0; rt < 4; rt++)
        #pragma unroll
        for (int kt = 0; kt < 4; kt++)
            ah[rt][kt] = *(const bf16x8*)&tile[(rt * 16 + m) * 136 + kt * 32 + quad * 8];

    #pragma unroll
    for (int ft = 0; ft < 2; ft++) {
        int f = wave * 32 + ft * 16 + m;
        bf16x8 bg[4];
        #pragma unroll
        for (int kt = 0; kt < 4; kt++)
            bg[kt] = *(const bf16x8*)(WTg + f * 128 + kt * 32 + quad * 8);
        #pragma unroll
        for (int rt = 0; rt < 4; rt++) {
            f32x4 acc = {0,0,0,0};
            #pragma unroll
            for (int kt = 0; kt < 4; kt++)
                acc = __builtin_amdgcn_mfma_f32_16x16x32_bf16(ah[rt][kt], bg[kt], acc, 0, 0, 0);
            #pragma unroll
            for (int r = 0; r < 4; r++) {
                int n = base + rt * 16 + quad * 4 + r;
                if (n < NN)   // pre-scale by dg[n]: folds GCN coeffs into the row
                    hb[n * 128 + f] = f2b(ldsdg[rt * 16 + quad * 4 + r] * acc[r]);
            }
        }
    }
}

// ---------------------------------------------------------------------------
// Fused gather + self-loop + relu->BN->linear. One wave per destination node.
// R7: half-wave per edge — lanes 0-31 take edge j, lanes 32-63 edge j+1; each
// lane covers 4 feats via one 8B load. 2x unroll -> 4 row-reads in flight
// (R6 was latency-bound: 2 in flight, VALUBusy 31%, HBM 18%).
// g[d] = dg[d]*(sum_e hb[src] + hb[d]);  hb already dg[s]-scaled.
// ---------------------------------------------------------------------------
__launch_bounds__(256)
__global__ void gat_out_k(const ushort_t* __restrict__ hb, const int* __restrict__ offs,
                          const int* __restrict__ cur, const int* __restrict__ bsrc,
                          const float* __restrict__ dg,
                          const void* __restrict__ gcnb, const float* __restrict__ coef,
                          const int* __restrict__ mode, void* __restrict__ out) {
    int wid  = (blockIdx.x * blockDim.x + threadIdx.x) >> 6;
    int lane = threadIdx.x & 63;
    if (wid >= NN) return;
    int half = lane >> 5, sl = lane & 31;
    int beg = offs[wid], end = cur[wid];   // cur post-fill == row end
    float a0 = 0.0f, a1 = 0.0f, a2 = 0.0f, a3 = 0.0f;
    int j = beg + half;
    for (; j + 2 < end; j += 4) {          // 2 edges per half-wave in flight
        int s0 = bsrc[j], s1 = bsrc[j + 2];
        uint2 r0 = *(const uint2*)(hb + s0 * 128 + sl * 4);
        uint2 r1 = *(const uint2*)(hb + s1 * 128 + sl * 4);
        a0 += b2f((ushort_t)(r0.x & 0xffffu)) + b2f((ushort_t)(r1.x & 0xffffu));
        a1 += b2f((ushort_t)(r0.x >> 16))     + b2f((ushort_t)(r1.x >> 16));
        a2 += b2f((ushort_t)(r0.y & 0xffffu)) + b2f((ushort_t)(r1.y & 0xffffu));
        a3 += b2f((ushort_t)(r0.y >> 16))     + b2f((ushort_t)(r1.y >> 16));
    }
    if (j < end) {
        int s = bsrc[j];
        uint2 r = *(const uint2*)(hb + s * 128 + sl * 4);
        a0 += b2f((ushort_t)(r.x & 0xffffu));
        a1 += b2f((ushort_t)(r.x >> 16));
        a2 += b2f((ushort_t)(r.y & 0xffffu));
        a3 += b2f((ushort_t)(r.y >> 16));
    }
    if (half == 0) {                       // self term once (pre-combine)
        uint2 r = *(const uint2*)(hb + wid * 128 + sl * 4);
        a0 += b2f((ushort_t)(r.x & 0xffffu));
        a1 += b2f((ushort_t)(r.x >> 16));
        a2 += b2f((ushort_t)(r.y & 0xffffu));
        a3 += b2f((ushort_t)(r.y >> 16));
    }
    // combine halves (same feats in lane l and l^32)
    a0 += __shfl_xor(a0, 32); a1 += __shfl_xor(a1, 32);
    a2 += __shfl_xor(a2, 32); a3 += __shfl_xor(a3, 32);
    int mf = mode[0];
    float d = dg[wid];
    int fb = sl * 4;
    float g0 = d * a0 + ldm(gcnb, fb,     mf);
    float g1 = d * a1 + ldm(gcnb, fb + 1, mf);
    float g2 = d * a2 + ldm(gcnb, fb + 2, mf);
    float g3 = d * a3 + ldm(gcnb, fb + 3, mf);
    float v = fmaxf(g0, 0.0f) * coef[512 + fb]
            + fmaxf(g1, 0.0f) * coef[512 + fb + 1]
            + fmaxf(g2, 0.0f) * coef[512 + fb + 2]
            + fmaxf(g3, 0.0f) * coef[512 + fb + 3];
    #pragma unroll
    for (int o = 32; o >= 1; o >>= 1) v += __shfl_down(v, o);   // sums both halves = 2x
    if (lane == 0) {
        float r = 0.5f * v + coef[640];
        if (mf) ((float*)out)[wid] = r;
        else    ((ushort_t*)out)[wid] = f2b(r);
    }
}

extern "C" void kernel_launch(void* const* d_in, const int* in_sizes, int n_in,
                              void* d_out, int out_size, void* d_ws, size_t ws_size,
                              hipStream_t stream) {
    if (ws_size < (size_t)WS_REQ) {   // diagnostic: finite 0.088 failure, not NaN
        fb_k<<<(out_size + 255) / 256, 256, 0, stream>>>((ushort_t*)d_out, out_size);
        return;
    }
    const void* x    = d_in[0];
    const int*  ei   = (const int*)d_in[1];
    // d_in[2] edge_weight: unused (ChebConv of zero state collapses to bias)
    const void* Wx   = d_in[3];
    const void* wc   = d_in[4];
    const void* bb   = d_in[5];
    // d_in[6] theta: unused
    const void* thb  = d_in[7];
    const void* gcnw = d_in[8];
    const void* gcnb = d_in[9];
    const void* gam  = d_in[10];
    const void* bet  = d_in[11];
    const void* mea  = d_in[12];
    const void* var  = d_in[13];
    const void* linw = d_in[14];
    const void* linb = d_in[15];

    char* ws = (char*)d_ws;
    ushort_t* hb   = (ushort_t*)(ws + OFF_HB);
    float*    dg   = (float*)   (ws + OFF_DG);
    int*      cnt  = (int*)     (ws + OFF_CNT);
    int*      offs = (int*)     (ws + OFF_OFFS);
    int*      cur  = (int*)     (ws + OFF_CUR);
    int*      bsrc = (int*)     (ws + OFF_BSRC);
    int*      part = (int*)     (ws + OFF_PART);
    int*      poff = (int*)     (ws + OFF_POFF);
    ushort_t* WT   = (ushort_t*)(ws + OFF_WT);
    float*    coef = (float*)   (ws + OFF_COEF);
    int*      mode = (int*)     (ws + OFF_MODE);

    init_k<<<NP + 1, 256, 0, stream>>>((const ushort_t*)x, cnt, mode);
    prep_k<<<65, 256, 0, stream>>>(Wx, gcnw, wc, bb, thb, gam, bet, mea, var, linw, linb, mode, WT, coef);
    degree_k<<<(NE + 255) / 256, 256, 0, stream>>>(ei, cnt);
    part_k<<<NP, 256, 0, stream>>>(cnt, part);
    scanpart_k<<<1, 256, 0, stream>>>(part, poff);
    emit_k<<<NP, 256, 0, stream>>>(cnt, poff, offs, cur, dg);
    fill_k<<<(NE + 255) / 256, 256, 0, stream>>>(ei, cur, bsrc);
    gates_k<<<(NN + 63) / 64, 256, 0, stream>>>(x, WT, coef, dg, mode, hb);
    gat_out_k<<<(NN * 64 + 255) / 256, 256, 0, stream>>>(hb, offs, cur, bsrc, dg, gcnb, coef, mode, d_out);
}